// Round 4
// baseline (581.631 us; speedup 1.0000x reference)
//
#include <hip/hip_runtime.h>
#include <stdint.h>

#define LL 2048
#define BB 8
#define DD 768
#define NROWS (LL*BB)
#define QKSCALE 0.03608439182435161f   // 1/sqrt(768)
#define EP 72                          // epilogue LDS row stride (bf16 elems)

typedef __attribute__((ext_vector_type(8))) short short8;
typedef __attribute__((ext_vector_type(4))) float f32x4;
typedef unsigned short u16;
typedef unsigned int u32;

__device__ __forceinline__ float bf2f(u16 u) {
    union { u32 u; float f; } c; c.u = ((u32)u) << 16; return c.f;
}
__device__ __forceinline__ u16 f2bf(float f) {
    union { float f; u32 u; } c; c.f = f;
    return (u16)((c.u + 0x8000u) >> 16);
}

// f32 -> bf16 bulk convert. blockIdx.y selects tensor; grid-stride over float4 groups.
__global__ __launch_bounds__(256)
void cvt_kernel(const float* __restrict__ s0, u16* __restrict__ d0,
                const float* __restrict__ s1, u16* __restrict__ d1,
                const float* __restrict__ s2, u16* __restrict__ d2,
                const float* __restrict__ s3, u16* __restrict__ d3,
                const float* __restrict__ s4, u16* __restrict__ d4,
                int nbig4, int nsmall4)
{
    const float* src; u16* dst; int n4;
    switch (blockIdx.y) {
        case 0: src = s0; dst = d0; n4 = nbig4; break;
        case 1: src = s1; dst = d1; n4 = nbig4; break;
        case 2: src = s2; dst = d2; n4 = nbig4; break;
        case 3: src = s3; dst = d3; n4 = nsmall4; break;
        default: src = s4; dst = d4; n4 = nsmall4; break;
    }
    for (int i = blockIdx.x * 256 + threadIdx.x; i < n4; i += gridDim.x * 256) {
        float4 v = *(const float4*)&src[i * 4];
        ushort4 o;
        o.x = f2bf(v.x); o.y = f2bf(v.y); o.z = f2bf(v.z); o.w = f2bf(v.w);
        *(ushort4*)&dst[i * 4] = o;
    }
}

__device__ __forceinline__ void gll16(const u16* g, u16* l) {
    __builtin_amdgcn_global_load_lds((const __attribute__((address_space(1))) u32*)g,
                                     (__attribute__((address_space(3))) u32*)l, 16, 0, 0);
}

// C = A @ B^T over K (bf16). 256x128 tile / block, 256 threads = 4 waves (2M x 2N),
// wave tile 128x64 (acc 8x4 f32x4). BK=32, double-buffered LDS 2 x 24KB = 48KB
// -> 2-3 independent blocks/CU (TLP overlap per m114/m97; single-block deep pipelines
// R1-R3 all hit the same ~28% MfmaUtil wall).
// Per K-tile: { stage(t+1) 6 x global_load_lds ; 12 ds_read_b128 ; 32 MFMA ;
//               vmcnt(0) ; s_barrier }  -- one barrier/tile; drain waits on loads
// issued a full tile earlier; residual stalls covered by co-resident blocks.
// LDS granule swizzle: slot s of row holds global granule s ^ (row&3); staging source
// pre-swizzled (linear gll dest); read slot = lg ^ (lr&3) -> conflict-free (8-cyc min).
// EPI 0: plain store. EPI 1: v=exp(v*QKSCALE), row-sum atomics to lsum.
// EPI 2: v=v*(1/lsum[row]) + bias[col]; BN col-stat atomics to stats.
template<int EPI>
__global__ __launch_bounds__(256, 3)
void gemm_bt256(const u16* __restrict__ A, int lda, long astr,
                const u16* __restrict__ B, int ldb, long bstr,
                u16* __restrict__ C, long cstr, int ldc,
                int K, int sw,
                float* __restrict__ lsum,
                const float* __restrict__ bias,
                float* __restrict__ stats)
{
    __shared__ u16 lds[24576];          // 48KB: 2 buffers x (A 8192 + B 4096 elems)

    const int tid = threadIdx.x;
    const int z = blockIdx.z;
    const int flat = blockIdx.y * gridDim.x + blockIdx.x;
    const int per = sw * gridDim.x;
    const int bm = (flat / per) * sw + (flat % sw);
    const int bn = (flat % per) / sw;
    const int m0 = bm * 256, n0 = bn * 128;

    const u16* Ab = A + (size_t)z * astr + (size_t)m0 * lda;
    const u16* Bb = B + (size_t)z * bstr + (size_t)n0 * ldb;
    u16* Cb = C + (size_t)z * cstr;

    const int lane = tid & 63, w = tid >> 6;
    const int wm = w >> 1, wn = w & 1;          // 2 x 2 wave grid; wave tile = 128 x 64
    const int lr = lane & 15, lg = lane >> 4;

    // ---- staging thread-constants: pre-swizzled global source, linear LDS dest ----
    // call j covers granule g = j*256+tid: row = j*64 + (tid>>2); src granule =
    // (tid&3) ^ (row&3) = (tid&3) ^ ((tid>>2)&3)  (j*64 ≡ 0 mod 4).
    const int arow = tid >> 2;
    const int gsw = (tid & 3) ^ (arow & 3);
    const u16* pA = Ab + (size_t)arow * lda + gsw * 8;
    const u16* pB = Bb + (size_t)arow * ldb + gsw * 8;
    const size_t lda64 = (size_t)64 * lda;
    const size_t ldb64 = (size_t)64 * ldb;

    // ---- ds_read thread-constants (elem offsets; row = 4 granules of 8 elems) ----
    const int slot = lg ^ (lr & 3);
    const int aof = (wm * 128 + lr) * 32 + slot * 8;
    const int bof = 8192 + (wn * 64 + lr) * 32 + slot * 8;

    f32x4 acc[8][4];
    const f32x4 zz = {0.f, 0.f, 0.f, 0.f};
    #pragma unroll
    for (int i = 0; i < 8; ++i)
        #pragma unroll
        for (int j = 0; j < 4; ++j) acc[i][j] = zz;

    const int nt = K >> 5;                      // K-tiles of 32 (24 or 64)

#define STAGE(KT, BUF)                                                   \
    do {                                                                 \
        gll16(pA + (KT),              lds + (BUF) + tid * 8);            \
        gll16(pA + (KT) + lda64,      lds + (BUF) + 2048 + tid * 8);     \
        gll16(pA + (KT) + 2 * lda64,  lds + (BUF) + 4096 + tid * 8);     \
        gll16(pA + (KT) + 3 * lda64,  lds + (BUF) + 6144 + tid * 8);     \
        gll16(pB + (KT),              lds + (BUF) + 8192 + tid * 8);     \
        gll16(pB + (KT) + ldb64,      lds + (BUF) + 10240 + tid * 8);    \
    } while (0)

    STAGE(0, 0);
    asm volatile("s_waitcnt vmcnt(0)" ::: "memory");
    asm volatile("s_barrier" ::: "memory");

    for (int t = 0; t < nt; ++t) {
        const int cb = (t & 1) * 12288;
        if (t + 1 < nt) STAGE((t + 1) * 32, 12288 - cb);
        short8 af[8], bf[4];
        #pragma unroll
        for (int mi = 0; mi < 8; ++mi) af[mi] = *(const short8*)&lds[cb + aof + mi * 512];
        #pragma unroll
        for (int ni = 0; ni < 4; ++ni) bf[ni] = *(const short8*)&lds[cb + bof + ni * 512];
        #pragma unroll
        for (int mi = 0; mi < 8; ++mi)
            #pragma unroll
            for (int ni = 0; ni < 4; ++ni)
                acc[mi][ni] = __builtin_amdgcn_mfma_f32_16x16x32_bf16(af[mi], bf[ni], acc[mi][ni], 0, 0, 0);
        asm volatile("s_waitcnt vmcnt(0)" ::: "memory");
        asm volatile("s_barrier" ::: "memory");
    }
#undef STAGE

    // ---- epilogue: frags -> per-wave LDS tile (64x72, two 64-row halves) -> stores ----
    u16* eb = lds + w * 4608;

    float invl[8][4]; float bcol[4];
    if constexpr (EPI == 2) {
        #pragma unroll
        for (int mi = 0; mi < 8; ++mi)
            #pragma unroll
            for (int r = 0; r < 4; ++r)
                invl[mi][r] = 1.0f / lsum[z * 2048 + m0 + wm * 128 + mi * 16 + lg * 4 + r];
        #pragma unroll
        for (int ni = 0; ni < 4; ++ni)
            bcol[ni] = bias[n0 + wn * 64 + ni * 16 + lr];
    }
    float csum[4] = {0, 0, 0, 0}, csq[4] = {0, 0, 0, 0};

    #pragma unroll
    for (int half = 0; half < 2; ++half) {
        #pragma unroll
        for (int mi = 0; mi < 4; ++mi) {
            const int MI = half * 4 + mi;
            float rsum[4] = {0, 0, 0, 0};
            #pragma unroll
            for (int ni = 0; ni < 4; ++ni) {
                #pragma unroll
                for (int r = 0; r < 4; ++r) {
                    float v = acc[MI][ni][r];
                    if constexpr (EPI == 1) { v = __expf(v * QKSCALE); rsum[r] += v; }
                    if constexpr (EPI == 2) { v = v * invl[MI][r] + bcol[ni]; csum[ni] += v; csq[ni] += v * v; }
                    eb[(mi * 16 + lg * 4 + r) * EP + ni * 16 + lr] = f2bf(v);
                }
            }
            if constexpr (EPI == 1) {
                #pragma unroll
                for (int r = 0; r < 4; ++r) {
                    float s = rsum[r];
                    s += __shfl_xor(s, 1); s += __shfl_xor(s, 2);
                    s += __shfl_xor(s, 4); s += __shfl_xor(s, 8);
                    if (lr == 0)
                        atomicAdd(&lsum[z * 2048 + m0 + wm * 128 + MI * 16 + lg * 4 + r], s);
                }
            }
        }
        #pragma unroll
        for (int c = 0; c < 8; ++c) {
            int row = c * 8 + (lane >> 3);
            short8 v = *(const short8*)&eb[row * EP + (lane & 7) * 8];
            *(short8*)&Cb[(size_t)(m0 + wm * 128 + half * 64 + row) * ldc + n0 + wn * 64 + (lane & 7) * 8] = v;
        }
    }
    if constexpr (EPI == 2) {
        #pragma unroll
        for (int ni = 0; ni < 4; ++ni) {
            float s = csum[ni], q = csq[ni];
            s += __shfl_xor(s, 16); s += __shfl_xor(s, 32);
            q += __shfl_xor(q, 16); q += __shfl_xor(q, 32);
            if (lg == 0) {
                atomicAdd(&stats[n0 + wn * 64 + ni * 16 + lr], s);
                atomicAdd(&stats[DD + n0 + wn * 64 + ni * 16 + lr], q);
            }
        }
    }
}

// Fold batch stats -> per-channel scale/shift. <<<2, 768>>>
__global__ void bn_params(const float* __restrict__ stats_a, const float* __restrict__ stats_v,
                          const float* __restrict__ g_a, const float* __restrict__ be_a,
                          const float* __restrict__ g_v, const float* __restrict__ be_v,
                          float* __restrict__ bnp_a, float* __restrict__ bnp_v)
{
    const int e = threadIdx.x;
    const float* st = (blockIdx.x == 0) ? stats_a : stats_v;
    const float* g  = (blockIdx.x == 0) ? g_a  : g_v;
    const float* be = (blockIdx.x == 0) ? be_a : be_v;
    float* bnp = (blockIdx.x == 0) ? bnp_a : bnp_v;
    float mean = st[e] * (1.0f / NROWS);
    float var  = st[DD + e] * (1.0f / NROWS) - mean * mean;
    float scale = g[e] * rsqrtf(var + 1e-5f);
    bnp[e]      = scale;
    bnp[DD + e] = be[e] - mean * scale;
}

// BN affine + PReLU (x2) + residual + row LayerNorm -> f32 out. One block per (l,b) row.
__global__ __launch_bounds__(256)
void final_kernel(const float* __restrict__ x,
                  const u16* __restrict__ y_a, const u16* __restrict__ y_v,
                  const float* __restrict__ bnp_a, const float* __restrict__ bnp_v,
                  const float* __restrict__ pra, const float* __restrict__ prv,
                  const float* __restrict__ lng, const float* __restrict__ lnb,
                  float* __restrict__ out)
{
    const int n = blockIdx.x;
    const int tid = threadIdx.x;
    __shared__ float vrow[DD];
    __shared__ float reds[4], reds2[4];
    const float aa = pra[0];
    const float av = prv[0];
    const size_t base = (size_t)n * DD;
    float s = 0.f, s2 = 0.f;
    for (int e = tid; e < DD; e += 256) {
        float ya = bf2f(y_a[base + e]) * bnp_a[e] + bnp_a[DD + e];
        ya = ya > 0.f ? ya : aa * ya;
        float yv = bf2f(y_v[base + e]) * bnp_v[e] + bnp_v[DD + e];
        yv = yv > 0.f ? yv : av * yv;
        float v = x[base + e] + ya + yv;
        vrow[e] = v;
        s += v; s2 += v * v;
    }
    for (int off = 32; off > 0; off >>= 1) { s += __shfl_xor(s, off); s2 += __shfl_xor(s2, off); }
    const int wv = tid >> 6;
    if ((tid & 63) == 0) { reds[wv] = s; reds2[wv] = s2; }
    __syncthreads();
    float ts  = reds[0] + reds[1] + reds[2] + reds[3];
    float ts2 = reds2[0] + reds2[1] + reds2[2] + reds2[3];
    float mean = ts * (1.0f / DD);
    float var  = ts2 * (1.0f / DD) - mean * mean;
    float rstd = rsqrtf(var + 1e-5f);
    for (int e = tid; e < DD; e += 256) {
        float o = (vrow[e] - mean) * rstd * lng[e] + lnb[e];
        out[base + e] = o;
    }
}

extern "C" void kernel_launch(void* const* d_in, const int* in_sizes, int n_in,
                              void* d_out, int out_size, void* d_ws, size_t ws_size,
                              hipStream_t stream)
{
    const float* x_a    = (const float*)d_in[0];
    const float* x_v    = (const float*)d_in[1];
    const float* x      = (const float*)d_in[2];
    const float* W_a    = (const float*)d_in[3];
    const float* b_a    = (const float*)d_in[4];
    const float* bn_a_g = (const float*)d_in[5];
    const float* bn_a_b = (const float*)d_in[6];
    const float* pr_a   = (const float*)d_in[7];
    const float* W_v    = (const float*)d_in[8];
    const float* b_v    = (const float*)d_in[9];
    const float* bn_v_g = (const float*)d_in[10];
    const float* bn_v_b = (const float*)d_in[11];
    const float* pr_v   = (const float*)d_in[12];
    const float* ln_g   = (const float*)d_in[13];
    const float* ln_b   = (const float*)d_in[14];

    // ---- workspace layout ----
    float* stats_a = (float*)d_ws;                 // 1536
    float* stats_v = stats_a + 1536;               // 1536
    float* bnp_a   = stats_v + 1536;               // 1536
    float* bnp_v   = bnp_a + 1536;                 // 1536
    float* lsum    = bnp_v + 1536;                 // 16*2048 (both branches)
    u16* xq_bf = (u16*)(lsum + 16 * 2048);         // NROWS*DD bf16
    u16* xa_bf = xq_bf + (size_t)NROWS * DD;       // NROWS*DD bf16, aliased as y_a
    u16* xv_bf = xa_bf + (size_t)NROWS * DD;       // NROWS*DD bf16, aliased as y_v
    u16* Wa_bf = xv_bf + (size_t)NROWS * DD;       // DD*DD
    u16* Wv_bf = Wa_bf + (size_t)DD * DD;          // DD*DD
    u16* UT    = Wv_bf + (size_t)DD * DD;          // nb * 768*2048 bf16
    u16* y_a = xa_bf;                              // alias: K2 writes after last kv read
    u16* y_v = xv_bf;
    size_t fixed_bytes = (size_t)((char*)UT - (char*)d_ws);

    int nb = 1;
    for (int cand = 8; cand >= 1; cand >>= 1) {
        size_t need = fixed_bytes + (size_t)cand * (3145728ull + 8388608ull);
        if (need <= ws_size) { nb = cand; break; }
    }
    u16* P = UT + (size_t)nb * (768 * 2048);       // nb * 2048*2048 bf16

    // zero BN stat accumulators + all lsum slots once up front
    hipMemsetAsync(stats_a, 0, (4 * 1536 + 16 * 2048) * sizeof(float), stream);

    // ---- bulk f32 -> bf16 conversion (x, x_a, x_v, W_a, W_v) ----
    cvt_kernel<<<dim3(3072, 5), 256, 0, stream>>>(
        x, xq_bf, x_a, xa_bf, x_v, xv_bf, W_a, Wa_bf, W_v, Wv_bf,
        NROWS * DD / 4, DD * DD / 4);

    const u16*   KVs[2]   = { xa_bf, xv_bf };
    const u16*   Ws[2]    = { Wa_bf, Wv_bf };
    const float* BIs[2]   = { b_a, b_v };
    u16*         Ys[2]    = { y_a, y_v };
    float*       STs[2]   = { stats_a, stats_v };

    for (int br = 0; br < 2; ++br) {
        const u16* kv = KVs[br];
        for (int c0 = 0; c0 < 8; c0 += nb) {
            float* lsum_bc = (nb == 8) ? (lsum + br * 8 * 2048) : lsum;
            if (nb != 8)
                hipMemsetAsync(lsum, 0, (size_t)nb * 2048 * sizeof(float), stream);
            // K0: U^T[e,m] = W @ KV^T   (M=768, N=2048, K=768) -> 3x16 tiles
            gemm_bt256<0><<<dim3(16, 3, nb), 256, 0, stream>>>(
                Ws[br], DD, 0, kv + c0 * DD, BB * DD, DD,
                UT, (long)768 * 2048, 2048, DD, 3, nullptr, nullptr, nullptr);
            // K1: P = exp(scale * Q @ KV^T)  (M=2048, N=2048, K=768) + row sums -> 8x16 tiles
            gemm_bt256<1><<<dim3(16, 8, nb), 256, 0, stream>>>(
                xq_bf + c0 * DD, BB * DD, DD, kv + c0 * DD, BB * DD, DD,
                P, (long)2048 * 2048, 2048, DD, 4, lsum_bc, nullptr, nullptr);
            // K2: y = (P @ U^T)/l + bias  (M=2048, N=768, K=2048) + BN stats -> 8x6 tiles
            gemm_bt256<2><<<dim3(6, 8, nb), 256, 0, stream>>>(
                P, 2048, (long)2048 * 2048, UT, 2048, (long)768 * 2048,
                Ys[br] + (size_t)c0 * DD, DD, BB * DD, 2048, 4, lsum_bc, BIs[br], STs[br]);
        }
    }

    bn_params<<<2, 768, 0, stream>>>(stats_a, stats_v, bn_a_g, bn_a_b, bn_v_g, bn_v_b, bnp_a, bnp_v);
    final_kernel<<<NROWS, 256, 0, stream>>>(x, y_a, y_v, bnp_a, bnp_v, pr_a, pr_v, ln_g, ln_b,
                                            (float*)d_out);
}

// Round 5
// 531.468 us; speedup vs baseline: 1.0944x; 1.0944x over previous
//
#include <hip/hip_runtime.h>
#include <stdint.h>

#define LL 2048
#define BB 8
#define DD 768
#define NROWS (LL*BB)
#define QKSCALE 0.03608439182435161f   // 1/sqrt(768)
#define EP 72                          // epilogue LDS row stride (bf16 elems)

typedef __attribute__((ext_vector_type(8))) short short8;
typedef __attribute__((ext_vector_type(4))) float f32x4;
typedef unsigned short u16;
typedef unsigned int u32;

__device__ __forceinline__ float bf2f(u16 u) {
    union { u32 u; float f; } c; c.u = ((u32)u) << 16; return c.f;
}
__device__ __forceinline__ u16 f2bf(float f) {
    union { float f; u32 u; } c; c.f = f;
    return (u16)((c.u + 0x8000u) >> 16);
}

// f32 -> bf16 bulk convert. blockIdx.y selects tensor; grid-stride over float4 groups.
__global__ __launch_bounds__(256)
void cvt_kernel(const float* __restrict__ s0, u16* __restrict__ d0,
                const float* __restrict__ s1, u16* __restrict__ d1,
                const float* __restrict__ s2, u16* __restrict__ d2,
                const float* __restrict__ s3, u16* __restrict__ d3,
                const float* __restrict__ s4, u16* __restrict__ d4,
                int nbig4, int nsmall4)
{
    const float* src; u16* dst; int n4;
    switch (blockIdx.y) {
        case 0: src = s0; dst = d0; n4 = nbig4; break;
        case 1: src = s1; dst = d1; n4 = nbig4; break;
        case 2: src = s2; dst = d2; n4 = nbig4; break;
        case 3: src = s3; dst = d3; n4 = nsmall4; break;
        default: src = s4; dst = d4; n4 = nsmall4; break;
    }
    for (int i = blockIdx.x * 256 + threadIdx.x; i < n4; i += gridDim.x * 256) {
        float4 v = *(const float4*)&src[i * 4];
        ushort4 o;
        o.x = f2bf(v.x); o.y = f2bf(v.y); o.z = f2bf(v.z); o.w = f2bf(v.w);
        *(ushort4*)&dst[i * 4] = o;
    }
}

__device__ __forceinline__ void gll16(const u16* g, u16* l) {
    __builtin_amdgcn_global_load_lds((const __attribute__((address_space(1))) u32*)g,
                                     (__attribute__((address_space(3))) u32*)l, 16, 0, 0);
}

// C = A @ B^T over K (bf16). 256x256 tile / block, 512 threads = 8 waves (2M x 4N),
// BK=64, 2 LDS buffers of 64 KiB = 128 KiB. R3's proven 4-phase/8-barrier schedule
// (best measured) -- inner loop UNCHANGED this round.
// NEW (R5): (1) bijective XCD swizzle of the slab-local block id: rid=(lid&7)*q+lid/8,
// q=nwg/8 (nwg%8==0 for all our grids) -> each XCD owns a contiguous tile chunk whose
// A/B panels fit its 4MB L2 -> staging L2-hits instead of ~900cy HBM misses.
// (2) dual-branch fusion: gridDim.z up to 16; z<8 = branch a, z>=8 = branch v via
// alt base pointers (zl = z&7 indexes strides; 16-slab workspaces pass alt = base+8*str).
// EPI 0: plain store. EPI 1: v=exp(v*QKSCALE), row-sum atomics to lsum (global-z slab).
// EPI 2: v=v*(1/lsum[z]) + bias[col]; BN col-stat atomics to stats.
template<int EPI>
__global__ __launch_bounds__(512, 2)
void gemm_bt256(const u16* __restrict__ A, const u16* __restrict__ Aalt, int lda, long astr,
                const u16* __restrict__ B, const u16* __restrict__ Balt, int ldb, long bstr,
                u16* __restrict__ C, u16* __restrict__ Calt, long cstr, int ldc,
                int K, int sw,
                float* __restrict__ lsum,
                const float* __restrict__ bias, const float* __restrict__ biasAlt,
                float* __restrict__ stats, float* __restrict__ statsAlt)
{
    __shared__ u16 lds[65536];          // 128 KiB: 2 buffers x (A 16384 + B 16384 elems)

    const int tid = threadIdx.x;
    const int z = blockIdx.z;
    const int zl = z & 7;
    const bool hi = z >= 8;

    // ---- XCD-aware bijective block remap, then supertile decomposition ----
    const int lid = blockIdx.y * gridDim.x + blockIdx.x;
    const int nwg = gridDim.x * gridDim.y;      // 64 or 24; % 8 == 0
    const int q = nwg >> 3;
    const int rid = (lid & 7) * q + (lid >> 3);
    const int per = sw * gridDim.x;
    const int bm = (rid / per) * sw + (rid % sw);
    const int bn = (rid % per) / sw;
    const int m0 = bm * 256, n0 = bn * 256;

    const u16* Ab = (hi ? Aalt : A) + (size_t)zl * astr + (size_t)m0 * lda;
    const u16* Bb = (hi ? Balt : B) + (size_t)zl * bstr + (size_t)n0 * ldb;
    u16* Cb = (hi ? Calt : C) + (size_t)zl * cstr;

    const int lane = tid & 63, w = tid >> 6;
    const int wm = w >> 2, wn = w & 3;          // 2 x 4 wave grid; wave tile = 128 x 64
    const int lr = lane & 15, lg = lane >> 4;

    // ---- staging thread-constants: pre-swizzled global source, linear LDS dest ----
    const int tr = tid >> 3;                          // row-in-half 0..63
    const int sg = (tid & 7) ^ ((tid >> 3) & 7);      // source col granule (swizzle)
    const u16* pA = Ab + (size_t)tr * lda + sg * 8;
    const u16* pB = Bb + (size_t)tr * ldb + sg * 8;
    const size_t lda64 = (size_t)64 * lda;
    const size_t ldb64 = (size_t)64 * ldb;

    // ---- ds_read thread-constants (elem offsets; row = 8 granules of 8 elems) ----
    const int sl0 = (lg) ^ (lr & 7);
    const int sl1 = (4 + lg) ^ (lr & 7);
    const int aro = wm * 128 + lr;
    const int bro = wn * 64 + lr;
    const int aof0 = aro * 64 + sl0 * 8;
    const int aof1 = aro * 64 + sl1 * 8;
    const int bof0 = 16384 + bro * 64 + sl0 * 8;
    const int bof1 = 16384 + bro * 64 + sl1 * 8;

    f32x4 acc[8][4];
    const f32x4 zz = {0.f, 0.f, 0.f, 0.f};
    #pragma unroll
    for (int i = 0; i < 8; ++i)
        #pragma unroll
        for (int j = 0; j < 4; ++j) acc[i][j] = zz;

    const int nt = K >> 6;                      // K-tiles of 64 (12 or 32; even, >=4)

    short8 af[4][2], b01[2][2], b23[2][2];

    // ---- prologue: A(0),B(0) -> buf0; B(1) -> buf1. vmcnt(4): B(1) stays in flight ----
    gll16(pA,             lds + tid * 8);
    gll16(pA + lda64,     lds + 4096 + tid * 8);
    gll16(pA + 2 * lda64, lds + 8192 + tid * 8);
    gll16(pA + 3 * lda64, lds + 12288 + tid * 8);
    gll16(pB,             lds + 16384 + tid * 8);
    gll16(pB + ldb64,     lds + 20480 + tid * 8);
    gll16(pB + 2 * ldb64, lds + 24576 + tid * 8);
    gll16(pB + 3 * ldb64, lds + 28672 + tid * 8);
    gll16(pB + 64,             lds + 32768 + 16384 + tid * 8);
    gll16(pB + 64 + ldb64,     lds + 32768 + 20480 + tid * 8);
    gll16(pB + 64 + 2 * ldb64, lds + 32768 + 24576 + tid * 8);
    gll16(pB + 64 + 3 * ldb64, lds + 32768 + 28672 + tid * 8);
    asm volatile("s_waitcnt vmcnt(4)" ::: "memory");
    asm volatile("s_barrier" ::: "memory");

#define LGKM0()  do { asm volatile("s_waitcnt lgkmcnt(0)" ::: "memory"); \
                      __builtin_amdgcn_sched_barrier(0); } while (0)
#define BARR()   asm volatile("s_barrier" ::: "memory")

#define TILE(T, DB, STA, STB, VM)                                                       \
    {                                                                                   \
        const int T_ = (T);                                                             \
        const u16* sA = pA + (size_t)(T_ + 1) * 64;                                     \
        const u16* sB = pB + (size_t)(T_ + 2) * 64;                                     \
        const int DBX = (DB) ^ 32768;                                                   \
        /* ---- P1: read a(mi0-3), b(ni0-1); stage A(T+1) half0 -> other buf ---- */    \
        _Pragma("unroll")                                                               \
        for (int mi = 0; mi < 4; ++mi) {                                                \
            af[mi][0] = *(const short8*)&lds[(DB) + aof0 + mi * 1024];                  \
            af[mi][1] = *(const short8*)&lds[(DB) + aof1 + mi * 1024];                  \
        }                                                                               \
        _Pragma("unroll")                                                               \
        for (int ni = 0; ni < 2; ++ni) {                                                \
            b01[ni][0] = *(const short8*)&lds[(DB) + bof0 + ni * 1024];                 \
            b01[ni][1] = *(const short8*)&lds[(DB) + bof1 + ni * 1024];                 \
        }                                                                               \
        if (STA) { gll16(sA, lds + DBX + tid * 8);                                      \
                   gll16(sA + lda64, lds + DBX + 4096 + tid * 8); }                     \
        BARR();                                                                         \
        LGKM0();                                                                        \
        __builtin_amdgcn_s_setprio(1);                                                  \
        _Pragma("unroll")                                                               \
        for (int mi = 0; mi < 4; ++mi)                                                  \
            _Pragma("unroll")                                                           \
            for (int ni = 0; ni < 2; ++ni) {                                            \
                acc[mi][ni] = __builtin_amdgcn_mfma_f32_16x16x32_bf16(af[mi][0], b01[ni][0], acc[mi][ni], 0, 0, 0); \
                acc[mi][ni] = __builtin_amdgcn_mfma_f32_16x16x32_bf16(af[mi][1], b01[ni][1], acc[mi][ni], 0, 0, 0); \
            }                                                                           \
        __builtin_amdgcn_s_setprio(0);                                                  \
        BARR();                                                                         \
        /* ---- P2: read b(ni2-3); stage A(T+1) half1 ---- */                           \
        _Pragma("unroll")                                                               \
        for (int ni = 0; ni < 2; ++ni) {                                                \
            b23[ni][0] = *(const short8*)&lds[(DB) + bof0 + 2048 + ni * 1024];          \
            b23[ni][1] = *(const short8*)&lds[(DB) + bof1 + 2048 + ni * 1024];          \
        }                                                                               \
        if (STA) { gll16(sA + 2 * lda64, lds + DBX + 8192 + tid * 8);                   \
                   gll16(sA + 3 * lda64, lds + DBX + 12288 + tid * 8); }                \
        BARR();                                                                         \
        LGKM0();                                                                        \
        __builtin_amdgcn_s_setprio(1);                                                  \
        _Pragma("unroll")                                                               \
        for (int mi = 0; mi < 4; ++mi)                                                  \
            _Pragma("unroll")                                                           \
            for (int ni = 0; ni < 2; ++ni) {                                            \
                acc[mi][ni + 2] = __builtin_amdgcn_mfma_f32_16x16x32_bf16(af[mi][0], b23[ni][0], acc[mi][ni + 2], 0, 0, 0); \
                acc[mi][ni + 2] = __builtin_amdgcn_mfma_f32_16x16x32_bf16(af[mi][1], b23[ni][1], acc[mi][ni + 2], 0, 0, 0); \
            }                                                                           \
        __builtin_amdgcn_s_setprio(0);                                                  \
        BARR();                                                                         \
        /* ---- P3: read a(mi4-7); stage B(T+2) half0 -> this buf ---- */               \
        _Pragma("unroll")                                                               \
        for (int mi = 0; mi < 4; ++mi) {                                                \
            af[mi][0] = *(const short8*)&lds[(DB) + aof0 + 4096 + mi * 1024];           \
            af[mi][1] = *(const short8*)&lds[(DB) + aof1 + 4096 + mi * 1024];           \
        }                                                                               \
        if (STB) { gll16(sB, lds + (DB) + 16384 + tid * 8);                             \
                   gll16(sB + ldb64, lds + (DB) + 20480 + tid * 8); }                   \
        BARR();                                                                         \
        LGKM0();                                                                        \
        __builtin_amdgcn_s_setprio(1);                                                  \
        _Pragma("unroll")                                                               \
        for (int mi = 0; mi < 4; ++mi)                                                  \
            _Pragma("unroll")                                                           \
            for (int ni = 0; ni < 2; ++ni) {                                            \
                acc[mi + 4][ni] = __builtin_amdgcn_mfma_f32_16x16x32_bf16(af[mi][0], b01[ni][0], acc[mi + 4][ni], 0, 0, 0); \
                acc[mi + 4][ni] = __builtin_amdgcn_mfma_f32_16x16x32_bf16(af[mi][1], b01[ni][1], acc[mi + 4][ni], 0, 0, 0); \
            }                                                                           \
        __builtin_amdgcn_s_setprio(0);                                                  \
        BARR();                                                                         \
        /* ---- P4: no reads; stage B(T+2) half1; counted vmcnt guards tile T+1 ---- */ \
        if (STB) { gll16(sB + 2 * ldb64, lds + (DB) + 24576 + tid * 8);                 \
                   gll16(sB + 3 * ldb64, lds + (DB) + 28672 + tid * 8); }               \
        if ((VM) == 4)      { asm volatile("s_waitcnt vmcnt(4)" ::: "memory"); }        \
        else if ((VM) == 0) { asm volatile("s_waitcnt vmcnt(0)" ::: "memory"); }        \
        BARR();                                                                         \
        __builtin_amdgcn_s_setprio(1);                                                  \
        _Pragma("unroll")                                                               \
        for (int mi = 0; mi < 4; ++mi)                                                  \
            _Pragma("unroll")                                                           \
            for (int ni = 0; ni < 2; ++ni) {                                            \
                acc[mi + 4][ni + 2] = __builtin_amdgcn_mfma_f32_16x16x32_bf16(af[mi][0], b23[ni][0], acc[mi + 4][ni + 2], 0, 0, 0); \
                acc[mi + 4][ni + 2] = __builtin_amdgcn_mfma_f32_16x16x32_bf16(af[mi][1], b23[ni][1], acc[mi + 4][ni + 2], 0, 0, 0); \
            }                                                                           \
        __builtin_amdgcn_s_setprio(0);                                                  \
        BARR();                                                                         \
    }

    for (int t = 0; t + 2 < nt; t += 2) {
        TILE(t, 0, 1, 1, 4)
        TILE(t + 1, 32768, 1, 1, 4)
    }
    TILE(nt - 2, 0, 1, 0, 0)
    TILE(nt - 1, 32768, 0, 0, -1)
#undef TILE
#undef LGKM0
#undef BARR

    // ---- epilogue: frags -> per-wave LDS tile (64x72, two 64-row halves) -> stores ----
    u16* eb = lds + w * 4608;

    const float* biasP = hi ? biasAlt : bias;
    float* statsP = hi ? statsAlt : stats;

    float invl[8][4]; float bcol[4];
    if constexpr (EPI == 2) {
        #pragma unroll
        for (int mi = 0; mi < 8; ++mi)
            #pragma unroll
            for (int r = 0; r < 4; ++r)
                invl[mi][r] = 1.0f / lsum[z * 2048 + m0 + wm * 128 + mi * 16 + lg * 4 + r];
        #pragma unroll
        for (int ni = 0; ni < 4; ++ni)
            bcol[ni] = biasP[n0 + wn * 64 + ni * 16 + lr];
    }
    float csum[4] = {0, 0, 0, 0}, csq[4] = {0, 0, 0, 0};

    #pragma unroll
    for (int half = 0; half < 2; ++half) {
        #pragma unroll
        for (int mi = 0; mi < 4; ++mi) {
            const int MI = half * 4 + mi;
            float rsum[4] = {0, 0, 0, 0};
            #pragma unroll
            for (int ni = 0; ni < 4; ++ni) {
                #pragma unroll
                for (int r = 0; r < 4; ++r) {
                    float v = acc[MI][ni][r];
                    if constexpr (EPI == 1) { v = __expf(v * QKSCALE); rsum[r] += v; }
                    if constexpr (EPI == 2) { v = v * invl[MI][r] + bcol[ni]; csum[ni] += v; csq[ni] += v * v; }
                    eb[(mi * 16 + lg * 4 + r) * EP + ni * 16 + lr] = f2bf(v);
                }
            }
            if constexpr (EPI == 1) {
                #pragma unroll
                for (int r = 0; r < 4; ++r) {
                    float s = rsum[r];
                    s += __shfl_xor(s, 1); s += __shfl_xor(s, 2);
                    s += __shfl_xor(s, 4); s += __shfl_xor(s, 8);
                    if (lr == 0)
                        atomicAdd(&lsum[z * 2048 + m0 + wm * 128 + MI * 16 + lg * 4 + r], s);
                }
            }
        }
        #pragma unroll
        for (int c = 0; c < 8; ++c) {
            int row = c * 8 + (lane >> 3);
            short8 v = *(const short8*)&eb[row * EP + (lane & 7) * 8];
            *(short8*)&Cb[(size_t)(m0 + wm * 128 + half * 64 + row) * ldc + n0 + wn * 64 + (lane & 7) * 8] = v;
        }
    }
    if constexpr (EPI == 2) {
        #pragma unroll
        for (int ni = 0; ni < 4; ++ni) {
            float s = csum[ni], q2 = csq[ni];
            s += __shfl_xor(s, 16); s += __shfl_xor(s, 32);
            q2 += __shfl_xor(q2, 16); q2 += __shfl_xor(q2, 32);
            if (lg == 0) {
                atomicAdd(&statsP[n0 + wn * 64 + ni * 16 + lr], s);
                atomicAdd(&statsP[DD + n0 + wn * 64 + ni * 16 + lr], q2);
            }
        }
    }
}

// Fold batch stats -> per-channel scale/shift. <<<2, 768>>>
__global__ void bn_params(const float* __restrict__ stats_a, const float* __restrict__ stats_v,
                          const float* __restrict__ g_a, const float* __restrict__ be_a,
                          const float* __restrict__ g_v, const float* __restrict__ be_v,
                          float* __restrict__ bnp_a, float* __restrict__ bnp_v)
{
    const int e = threadIdx.x;
    const float* st = (blockIdx.x == 0) ? stats_a : stats_v;
    const float* g  = (blockIdx.x == 0) ? g_a  : g_v;
    const float* be = (blockIdx.x == 0) ? be_a : be_v;
    float* bnp = (blockIdx.x == 0) ? bnp_a : bnp_v;
    float mean = st[e] * (1.0f / NROWS);
    float var  = st[DD + e] * (1.0f / NROWS) - mean * mean;
    float scale = g[e] * rsqrtf(var + 1e-5f);
    bnp[e]      = scale;
    bnp[DD + e] = be[e] - mean * scale;
}

// BN affine + PReLU (x2) + residual + row LayerNorm -> f32 out. One block per (l,b) row.
__global__ __launch_bounds__(256)
void final_kernel(const float* __restrict__ x,
                  const u16* __restrict__ y_a, const u16* __restrict__ y_v,
                  const float* __restrict__ bnp_a, const float* __restrict__ bnp_v,
                  const float* __restrict__ pra, const float* __restrict__ prv,
                  const float* __restrict__ lng, const float* __restrict__ lnb,
                  float* __restrict__ out)
{
    const int n = blockIdx.x;
    const int tid = threadIdx.x;
    __shared__ float vrow[DD];
    __shared__ float reds[4], reds2[4];
    const float aa = pra[0];
    const float av = prv[0];
    const size_t base = (size_t)n * DD;
    float s = 0.f, s2 = 0.f;
    for (int e = tid; e < DD; e += 256) {
        float ya = bf2f(y_a[base + e]) * bnp_a[e] + bnp_a[DD + e];
        ya = ya > 0.f ? ya : aa * ya;
        float yv = bf2f(y_v[base + e]) * bnp_v[e] + bnp_v[DD + e];
        yv = yv > 0.f ? yv : av * yv;
        float v = x[base + e] + ya + yv;
        vrow[e] = v;
        s += v; s2 += v * v;
    }
    for (int off = 32; off > 0; off >>= 1) { s += __shfl_xor(s, off); s2 += __shfl_xor(s2, off); }
    const int wv = tid >> 6;
    if ((tid & 63) == 0) { reds[wv] = s; reds2[wv] = s2; }
    __syncthreads();
    float ts  = reds[0] + reds[1] + reds[2] + reds[3];
    float ts2 = reds2[0] + reds2[1] + reds2[2] + reds2[3];
    float mean = ts * (1.0f / DD);
    float var  = ts2 * (1.0f / DD) - mean * mean;
    float rstd = rsqrtf(var + 1e-5f);
    for (int e = tid; e < DD; e += 256) {
        float o = (vrow[e] - mean) * rstd * lng[e] + lnb[e];
        out[base + e] = o;
    }
}

extern "C" void kernel_launch(void* const* d_in, const int* in_sizes, int n_in,
                              void* d_out, int out_size, void* d_ws, size_t ws_size,
                              hipStream_t stream)
{
    const float* x_a    = (const float*)d_in[0];
    const float* x_v    = (const float*)d_in[1];
    const float* x      = (const float*)d_in[2];
    const float* W_a    = (const float*)d_in[3];
    const float* b_a    = (const float*)d_in[4];
    const float* bn_a_g = (const float*)d_in[5];
    const float* bn_a_b = (const float*)d_in[6];
    const float* pr_a   = (const float*)d_in[7];
    const float* W_v    = (const float*)d_in[8];
    const float* b_v    = (const float*)d_in[9];
    const float* bn_v_g = (const float*)d_in[10];
    const float* bn_v_b = (const float*)d_in[11];
    const float* pr_v   = (const float*)d_in[12];
    const float* ln_g   = (const float*)d_in[13];
    const float* ln_b   = (const float*)d_in[14];

    // ---- workspace layout ----
    float* stats_a = (float*)d_ws;                 // 1536
    float* stats_v = stats_a + 1536;               // 1536
    float* bnp_a   = stats_v + 1536;               // 1536
    float* bnp_v   = bnp_a + 1536;                 // 1536
    float* lsum    = bnp_v + 1536;                 // 16*2048 (both branches)
    u16* xq_bf = (u16*)(lsum + 16 * 2048);         // NROWS*DD bf16
    u16* xa_bf = xq_bf + (size_t)NROWS * DD;       // NROWS*DD bf16, aliased as y_a
    u16* xv_bf = xa_bf + (size_t)NROWS * DD;       // NROWS*DD bf16, aliased as y_v
    u16* Wa_bf = xv_bf + (size_t)NROWS * DD;       // DD*DD
    u16* Wv_bf = Wa_bf + (size_t)DD * DD;          // DD*DD
    u16* UT    = Wv_bf + (size_t)DD * DD;          // slabs of 768*2048 bf16
    u16* y_a = xa_bf;                              // alias: K2 writes after last kv read
    u16* y_v = xv_bf;
    size_t fixed_bytes = (size_t)((char*)UT - (char*)d_ws);

    const size_t UTS = (size_t)768 * 2048;         // elems per UT slab
    const size_t PS  = (size_t)2048 * 2048;        // elems per P slab

    // zero BN stat accumulators + all lsum slots once up front
    hipMemsetAsync(stats_a, 0, (4 * 1536 + 16 * 2048) * sizeof(float), stream);

    // ---- bulk f32 -> bf16 conversion (x, x_a, x_v, W_a, W_v) ----
    cvt_kernel<<<dim3(3072, 5), 256, 0, stream>>>(
        x, xq_bf, x_a, xa_bf, x_v, xv_bf, W_a, Wa_bf, W_v, Wv_bf,
        NROWS * DD / 4, DD * DD / 4);

    bool fused = fixed_bytes + 16ull * (UTS + PS) * 2ull <= ws_size;

    if (fused) {
        u16* P = UT + 16 * UTS;
        // K0: U^T = W @ KV^T  (M=768, N=2048, K=768), z=0..15 both branches
        gemm_bt256<0><<<dim3(8, 3, 16), 512, 0, stream>>>(
            Wa_bf, Wv_bf, DD, 0,
            xa_bf, xv_bf, BB * DD, DD,
            UT, UT + 8 * UTS, (long)UTS, 2048, DD, 3,
            nullptr, nullptr, nullptr, nullptr, nullptr);
        // K1: P = exp(scale * Q @ KV^T) + row sums (M=2048, N=2048, K=768)
        gemm_bt256<1><<<dim3(8, 8, 16), 512, 0, stream>>>(
            xq_bf, xq_bf, BB * DD, DD,
            xa_bf, xv_bf, BB * DD, DD,
            P, P + 8 * PS, (long)PS, 2048, DD, 4,
            lsum, nullptr, nullptr, nullptr, nullptr);
        // K2: y = (P @ U^T)/l + bias + BN stats (M=2048, N=768, K=2048)
        gemm_bt256<2><<<dim3(3, 8, 16), 512, 0, stream>>>(
            P, P + 8 * PS, 2048, (long)PS,
            UT, UT + 8 * UTS, 2048, (long)UTS,
            y_a, y_v, DD, BB * DD, 2048, 4,
            lsum, b_a, b_v, stats_a, stats_v);
    } else {
        int nb = 1;
        for (int cand = 8; cand >= 1; cand >>= 1) {
            size_t need = fixed_bytes + (size_t)cand * (UTS + PS) * 2ull;
            if (need <= ws_size) { nb = cand; break; }
        }
        u16* P = UT + (size_t)nb * UTS;

        const u16*   KVs[2]   = { xa_bf, xv_bf };
        const u16*   Ws[2]    = { Wa_bf, Wv_bf };
        const float* BIs[2]   = { b_a, b_v };
        u16*         Ys[2]    = { y_a, y_v };
        float*       STs[2]   = { stats_a, stats_v };

        for (int br = 0; br < 2; ++br) {
            const u16* kv = KVs[br];
            for (int c0 = 0; c0 < 8; c0 += nb) {
                float* lsum_bc = (nb == 8) ? (lsum + br * 8 * 2048) : lsum;
                if (nb != 8)
                    hipMemsetAsync(lsum, 0, (size_t)nb * 2048 * sizeof(float), stream);
                gemm_bt256<0><<<dim3(8, 3, nb), 512, 0, stream>>>(
                    Ws[br], Ws[br], DD, 0, kv + c0 * DD, kv + c0 * DD, BB * DD, DD,
                    UT, UT, (long)UTS, 2048, DD, 3,
                    nullptr, nullptr, nullptr, nullptr, nullptr);
                gemm_bt256<1><<<dim3(8, 8, nb), 512, 0, stream>>>(
                    xq_bf + c0 * DD, xq_bf + c0 * DD, BB * DD, DD,
                    kv + c0 * DD, kv + c0 * DD, BB * DD, DD,
                    P, P, (long)PS, 2048, DD, 4,
                    lsum_bc, nullptr, nullptr, nullptr, nullptr);
                gemm_bt256<2><<<dim3(3, 8, nb), 512, 0, stream>>>(
                    P, P, 2048, (long)PS, UT, UT, 2048, (long)UTS,
                    Ys[br] + (size_t)c0 * DD, Ys[br] + (size_t)c0 * DD, DD, BB * DD, 2048, 4,
                    lsum_bc, BIs[br], BIs[br], STs[br], STs[br]);
            }
        }
    }

    bn_params<<<2, 768, 0, stream>>>(stats_a, stats_v, bn_a_g, bn_a_b, bn_v_g, bn_v_b, bnp_a, bnp_v);
    final_kernel<<<NROWS, 256, 0, stream>>>(x, y_a, y_v, bnp_a, bnp_v, pr_a, pr_v, ln_g, ln_b,
                                            (float*)d_out);
}